// Round 5
// baseline (1818.884 us; speedup 1.0000x reference)
//
#include <hip/hip_runtime.h>
#include <hip/hip_bf16.h>
#include <math.h>

#define B_   4096
#define T_   16
#define F_   256
#define U_   512
#define M_   8
#define K_   768    // F+U
#define NRS  4096   // U*M
#define NC   8192   // combined R|S output cols
#define LNT  1.1512925f  // 0.5*ln(10)

typedef __bf16 bf16_t;
typedef bf16_t bf16x8 __attribute__((ext_vector_type(8)));
typedef bf16_t bf16x4 __attribute__((ext_vector_type(4)));
typedef float  f32x4  __attribute__((ext_vector_type(4)));

__device__ inline void gl_lds16(const void* g, void* lds) {
    __builtin_amdgcn_global_load_lds(
        (const __attribute__((address_space(1))) unsigned int*)g,
        (__attribute__((address_space(3))) unsigned int*)lds, 16, 0, 0);
}

#define VMCNT(n) asm volatile("s_waitcnt vmcnt(" #n ")" ::: "memory")
#define LGKM0()  asm volatile("s_waitcnt lgkmcnt(0)" ::: "memory")
#define BAR()    __builtin_amdgcn_s_barrier()

// ---------------------------------------------------------------------------
// Half-tile format (A/B operands, pre-tiled): [128 rows][8 chunks][8 bf16],
// 16 KB. Chunk q of row r holds SOURCE columns (q ^ (r&7))*8..+7 (bank-
// swizzle baked into data; 16 lanes at fixed chunk -> 2-way conflict = free).
// Staging one half-tile = 2 linear 16B loads/thread (512 thr), 1KB/wave/inst.
// ---------------------------------------------------------------------------
__device__ inline void stage_ht(const bf16_t* src, bf16_t* dst, int tid) {
    gl_lds16(src + tid * 8,        (char*)dst + tid * 16);
    gl_lds16(src + tid * 8 + 4096, (char*)dst + tid * 16 + 8192);
}

// ---------------------------------------------------------------------------
// Combined R|S GEMM — faithful m201 8-phase template. 256x256 tile, BK=64,
// 8 waves (2Mx4N), per-wave C 128x64 (acc[8][4] f32x4). LDS 128 KiB:
// [dbuf][half] 16KB half-tiles for A and B. 12 K-tiles = 6 iters x 8 phases.
// Per phase: {ds_read new subtile | stage half-tile(s)} ; BAR ; lgkm0 ;
// setprio(1) 16 MFMA setprio(0) ; [counted VMCNT] ; BAR.
// Phase reads per K-tile: p1 A-mh0(8)+B-nh0(4), p2 B-nh1(4), p3 A-mh1(8),
// p4 none (B half resident in b[8] across phases).
// Stage placement (first hazard-free phase after target's last read):
//   p3 B(E+2,h0)  p4 B(E+2,h1)  p5 A(E+2,h0)  p6 A(E+2,h1)
//   p7 B(E+3,h0)  p8 B(E+3,h1)+A(E+3,h0)+A(E+3,h1)
// vmcnt derivation (2 loads/half-tile/thread, issue order as above):
//   p4: outstanding = 8(prev p7/p8, = this iter's dbuf1) + 4(p3,p4)
//       -> VMCNT(4) completes dbuf1 before p5 reads it.
//   p8: outstanding = 4 + 12(p5..p8) -> VMCNT(8) completes dbuf0 tile E+2
//       (p3..p6 stages) before next iter's p1; keeps p7/p8's 8 in flight.
// Never vmcnt(0) in steady state (T4).
// ---------------------------------------------------------------------------
__global__ __launch_bounds__(512, 1) void gemm_rs_v8(
    const bf16_t* __restrict__ xt_t,   // [16 mp][4 kt][2 half][128*64]
    const bf16_t* __restrict__ ht,     // [16 mp][8 kt][2 half][128*64]
    const bf16_t* __restrict__ Bt,     // [32 np][12 kt][2 half][128*64]
    const float*  __restrict__ biasP,  // [NC] (perm)
    const bf16_t* __restrict__ hhat,   // [B_][NRS]
    bf16_t* __restrict__ rh,           // [B_][U_]
    bf16_t* __restrict__ sbuf)         // [B_][NRS]
{
    __shared__ __attribute__((aligned(16))) bf16_t Ah[2][2][8192];  // 64 KiB
    __shared__ __attribute__((aligned(16))) bf16_t Bh[2][2][8192];  // 64 KiB

    const int tid  = threadIdx.x;
    const int lane = tid & 63;
    const int wave = tid >> 6;

    // Bijective XCD swizzle: XCD c owns a 4m x 16n rectangle (verified R2:
    // FETCH 118->53.5 MB, near-minimal).
    const int lin = blockIdx.y * 16 + blockIdx.x;
    const int xcd = lin & 7, q = lin >> 3;
    const int m0 = ((xcd >> 1) * 4 + (q & 3)) * 256;
    const int n0 = ((xcd & 1) * 16 + (q >> 2)) * 256;
    const int mp = m0 >> 8, np = n0 >> 8;

    const int wm = wave >> 2;          // 0..1 (A half = wm)
    const int wn = wave & 3;           // 0..3 (B half = wn>>1)
    const int lr = lane & 15;
    const int kq = lane >> 4;
    const int ck0 = (kq ^ (lr & 7)) * 8;   // ks=0 chunk; ks=1 -> ck0^32

    const bf16_t* Ab0 = &Ah[0][wm][0] + lr * 64;
    const bf16_t* Ab1 = &Ah[1][wm][0] + lr * 64;
    const bf16_t* Bb0 = &Bh[0][wn >> 1][0] + ((wn & 1) * 64 + lr) * 64;
    const bf16_t* Bb1 = &Bh[1][wn >> 1][0] + ((wn & 1) * 64 + lr) * 64;

    f32x4 acc[8][4] = {};
    bf16x8 a[8], b[8];

#define AS(T, H) ((T) < 4 ? xt_t + ((size_t)(mp * 4 + (T)) * 2 + (H)) * 8192  \
                          : ht  + ((size_t)(mp * 8 + (T) - 4) * 2 + (H)) * 8192)
#define BS(T, H) (Bt + ((size_t)(np * 12 + (T)) * 2 + (H)) * 8192)

#define RDA(P, mh) do{ const bf16_t* _p = (P) + (mh) * 4096;                   \
    a[0]=*(const bf16x8*)(_p+ck0);      a[1]=*(const bf16x8*)(_p+(ck0^32));    \
    a[2]=*(const bf16x8*)(_p+1024+ck0); a[3]=*(const bf16x8*)(_p+1024+(ck0^32)); \
    a[4]=*(const bf16x8*)(_p+2048+ck0); a[5]=*(const bf16x8*)(_p+2048+(ck0^32)); \
    a[6]=*(const bf16x8*)(_p+3072+ck0); a[7]=*(const bf16x8*)(_p+3072+(ck0^32)); }while(0)

#define RDB(P, nh) do{ const bf16_t* _p = (P) + (nh) * 2048;                   \
    b[(nh)*4+0]=*(const bf16x8*)(_p+ck0);                                      \
    b[(nh)*4+1]=*(const bf16x8*)(_p+(ck0^32));                                 \
    b[(nh)*4+2]=*(const bf16x8*)(_p+1024+ck0);                                 \
    b[(nh)*4+3]=*(const bf16x8*)(_p+1024+(ck0^32)); }while(0)

// 16 MFMA = one C-quadrant (mh,nh) over K=64. ks-outer: 8 independent, then
// 8 each depending 8 back (no back-to-back dependent pairs).
#define MMA(MH, NH) do{ __builtin_amdgcn_s_setprio(1);                         \
    _Pragma("unroll") for (int ai = 0; ai < 4; ++ai)                           \
      _Pragma("unroll") for (int bj = 0; bj < 2; ++bj)                         \
        acc[(MH)*4+ai][(NH)*2+bj] = __builtin_amdgcn_mfma_f32_16x16x32_bf16(   \
            a[ai*2+0], b[(NH)*4+bj*2+0], acc[(MH)*4+ai][(NH)*2+bj], 0, 0, 0);  \
    _Pragma("unroll") for (int ai = 0; ai < 4; ++ai)                           \
      _Pragma("unroll") for (int bj = 0; bj < 2; ++bj)                         \
        acc[(MH)*4+ai][(NH)*2+bj] = __builtin_amdgcn_mfma_f32_16x16x32_bf16(   \
            a[ai*2+1], b[(NH)*4+bj*2+1], acc[(MH)*4+ai][(NH)*2+bj], 0, 0, 0);  \
    __builtin_amdgcn_s_setprio(0); }while(0)

    // Prologue: stage dbuf0 (tile 0) then dbuf1 (tile 1); vmcnt(8) -> tile 0
    // landed, tile 1's 8 loads stay in flight (drained at iter0-p4's vmcnt(4)).
    stage_ht(AS(0, 0), &Ah[0][0][0], tid);
    stage_ht(AS(0, 1), &Ah[0][1][0], tid);
    stage_ht(BS(0, 0), &Bh[0][0][0], tid);
    stage_ht(BS(0, 1), &Bh[0][1][0], tid);
    stage_ht(AS(1, 0), &Ah[1][0][0], tid);
    stage_ht(AS(1, 1), &Ah[1][1][0], tid);
    stage_ht(BS(1, 0), &Bh[1][0][0], tid);
    stage_ht(BS(1, 1), &Bh[1][1][0], tid);
    VMCNT(8);
    BAR();

#define ITER_S(E) do{                                                          \
    RDA(Ab0,0); RDB(Bb0,0);                    BAR(); LGKM0(); MMA(0,0); BAR();\
    RDB(Bb0,1);                                BAR(); LGKM0(); MMA(0,1); BAR();\
    RDA(Ab0,1); stage_ht(BS((E)+2,0), &Bh[0][0][0], tid);                      \
                                               BAR(); LGKM0(); MMA(1,1); BAR();\
    stage_ht(BS((E)+2,1), &Bh[0][1][0], tid);                                  \
                                    BAR(); LGKM0(); MMA(1,0); VMCNT(4); BAR(); \
    RDA(Ab1,0); RDB(Bb1,0); stage_ht(AS((E)+2,0), &Ah[0][0][0], tid);          \
                                               BAR(); LGKM0(); MMA(0,0); BAR();\
    RDB(Bb1,1); stage_ht(AS((E)+2,1), &Ah[0][1][0], tid);                      \
                                               BAR(); LGKM0(); MMA(0,1); BAR();\
    RDA(Ab1,1); stage_ht(BS((E)+3,0), &Bh[1][0][0], tid);                      \
                                               BAR(); LGKM0(); MMA(1,1); BAR();\
    stage_ht(BS((E)+3,1), &Bh[1][1][0], tid);                                  \
    stage_ht(AS((E)+3,0), &Ah[1][0][0], tid);                                  \
    stage_ht(AS((E)+3,1), &Ah[1][1][0], tid);                                  \
                                    BAR(); LGKM0(); MMA(1,0); VMCNT(8); BAR(); \
}while(0)

#define ITER_L() do{                                                           \
    RDA(Ab0,0); RDB(Bb0,0);                    BAR(); LGKM0(); MMA(0,0); BAR();\
    RDB(Bb0,1);                                BAR(); LGKM0(); MMA(0,1); BAR();\
    RDA(Ab0,1);                                BAR(); LGKM0(); MMA(1,1); BAR();\
                                    BAR(); LGKM0(); MMA(1,0); VMCNT(0); BAR(); \
    RDA(Ab1,0); RDB(Bb1,0);                    BAR(); LGKM0(); MMA(0,0); BAR();\
    RDB(Bb1,1);                                BAR(); LGKM0(); MMA(0,1); BAR();\
    RDA(Ab1,1);                                BAR(); LGKM0(); MMA(1,1); BAR();\
                                               BAR(); LGKM0(); MMA(1,0);       \
}while(0)

    ITER_S(0);
    ITER_S(2);
    ITER_S(4);
    ITER_S(6);
    ITER_S(8);
    ITER_L();

#undef ITER_S
#undef ITER_L
#undef MMA
#undef RDA
#undef RDB
#undef AS
#undef BS

    // ------------------- fused softmax epilogue (unchanged math) -----------
    const int nb  = n0 + wn * 64;
    const int u3  = lane & 7;
    const int m0v = ((lane >> 3) & 1) * 4;
    const bool is_r = nb < NRS;

    float bj4[4];
#pragma unroll
    for (int j = 0; j < 4; ++j) bj4[j] = biasP[nb + j * 16 + lr];

#pragma unroll
    for (int mi = 0; mi < 8; ++mi) {
        const int rowb = m0 + wm * 128 + mi * 16 + kq * 4;
#pragma unroll
        for (int r = 0; r < 4; ++r) {
            const int row = rowb + r;
            float e[4], sum = 0.f;
#pragma unroll
            for (int j = 0; j < 4; ++j) {
                float v = acc[mi][j][r] + bj4[j];
                float d = v - (float)(m0v + j) * LNT;
                e[j] = __expf(-d * d);
                sum += e[j];
            }
            sum += __shfl_xor(sum, 8, 64);
            const float inv = 1.0f / sum;
            if (is_r) {
                bf16x4 h4 = *(const bf16x4*)(hhat + (size_t)row * NRS + nb + u3 * 8 + m0v);
                float rhv = 0.f;
#pragma unroll
                for (int j = 0; j < 4; ++j) rhv += e[j] * inv * (float)h4[j];
                rhv += __shfl_xor(rhv, 8, 64);
                if ((lane & 8) == 0)
                    rh[(size_t)row * U_ + (nb >> 3) + u3] = (bf16_t)rhv;
            } else {
                bf16x4 pv;
#pragma unroll
                for (int j = 0; j < 4; ++j) pv[j] = (bf16_t)(e[j] * inv);
                *(bf16x4*)(sbuf + (size_t)row * NRS + (nb - NRS) + u3 * 8 + m0v) = pv;
            }
        }
    }
}

// ---------------------------------------------------------------------------
// q GEMM (64x64 tiles, grid 64x8=512, 4 waves 2x2) + fused state update.
// A x-part / B from pre-tiled swizzled 64x64 tiles (linear staging); rh part
// staged scattered with inverse-swizzle. Reads un-XOR. Epilogue writes the
// TILED h (htile, half-tile format) consumed by the next step's gemm_rs_v8.
// ---------------------------------------------------------------------------
__global__ __launch_bounds__(256) void gemm_q_up(
    const bf16_t* __restrict__ xt_t,   // [16 mp][4 kt][2 half][128*64]
    const bf16_t* __restrict__ rh,     // [B_][U_]
    const bf16_t* __restrict__ Bqt,    // [8 np][12 kt][64*64] swz
    const float*  __restrict__ bq,
    const bf16_t* __restrict__ sbuf,
    bf16_t* __restrict__ hhat,
    bf16_t* __restrict__ hnext,        // hall slice t+1: [B_][U_]
    bf16_t* __restrict__ htile)        // [16 mp][8 kt][2 half][128*64]
{
    __shared__ __attribute__((aligned(16))) bf16_t As[4096];
    __shared__ __attribute__((aligned(16))) bf16_t Bs[4096];

    const int tid  = threadIdx.x;
    const int lane = tid & 63;
    const int wave = tid >> 6;
    const int m0 = blockIdx.x * 64;
    const int n0 = blockIdx.y * 64;
    const int wm = wave & 1;
    const int wn = wave >> 1;
    const int lr = lane & 15;
    const int kq = lane >> 4;
    const int ck0 = (kq ^ (lr & 7)) * 8;

    const int mp = m0 >> 8, half = (m0 >> 7) & 1, r0 = m0 & 127;
    const int rw = tid >> 3, q8 = tid & 7;

    f32x4 acc[2][2] = {};

    for (int kt = 0; kt < 12; ++kt) {
        __syncthreads();
        if (kt < 4) {
            const bf16_t* s = xt_t + ((size_t)(mp * 4 + kt) * 2 + half) * 8192 + r0 * 64;
            gl_lds16(s + tid * 8,        (char*)As + tid * 16);
            gl_lds16(s + tid * 8 + 2048, (char*)As + tid * 16 + 4096);
        } else {
            const int cb = (kt - 4) * 64;
            gl_lds16(rh + (size_t)(m0 + rw) * U_ + cb + ((q8 ^ (rw & 7)) * 8),
                     (char*)As + tid * 16);
            gl_lds16(rh + (size_t)(m0 + 32 + rw) * U_ + cb + ((q8 ^ (rw & 7)) * 8),
                     (char*)As + tid * 16 + 4096);
        }
        {
            const bf16_t* s = Bqt + (size_t)((n0 >> 6) * 12 + kt) * 4096;
            gl_lds16(s + tid * 8,        (char*)Bs + tid * 16);
            gl_lds16(s + tid * 8 + 2048, (char*)Bs + tid * 16 + 4096);
        }
        __syncthreads();

        bf16x8 af[4], bfr[4];
#pragma unroll
        for (int i = 0; i < 2; i++) {
            const bf16_t* pa = As + (wm * 32 + i * 16 + lr) * 64;
            const bf16_t* pb = Bs + (wn * 32 + i * 16 + lr) * 64;
            af[i * 2 + 0]  = *(const bf16x8*)(pa + ck0);
            af[i * 2 + 1]  = *(const bf16x8*)(pa + (ck0 ^ 32));
            bfr[i * 2 + 0] = *(const bf16x8*)(pb + ck0);
            bfr[i * 2 + 1] = *(const bf16x8*)(pb + (ck0 ^ 32));
        }
#pragma unroll
        for (int ks = 0; ks < 2; ks++)
#pragma unroll
            for (int i = 0; i < 2; i++)
#pragma unroll
                for (int j = 0; j < 2; j++)
                    acc[i][j] = __builtin_amdgcn_mfma_f32_16x16x32_bf16(
                        af[i * 2 + ks], bfr[j * 2 + ks], acc[i][j], 0, 0, 0);
    }

    const float DEC[8] = {0.0f, 0.9658531f, 0.9827783f, 0.9884856f,
                          0.9913518f, 0.9930754f, 0.9942261f, 0.9950489f};

#pragma unroll
    for (int i = 0; i < 2; i++) {
        const int rowb = m0 + wm * 32 + i * 16 + kq * 4;
#pragma unroll
        for (int j = 0; j < 2; j++) {
            const int u = n0 + wn * 32 + j * 16 + lr;
            const float bv = bq[u];
            const int kt2 = u >> 6, kc = u & 63;
#pragma unroll
            for (int r = 0; r < 4; r++) {
                const int row = rowb + r;
                const float qv = tanhf(acc[i][j][r] + bv);
                const size_t base = (size_t)row * NRS + u * 8;
                bf16x8 s8 = *(const bf16x8*)(sbuf + base);
                bf16x8 h8 = *(const bf16x8*)(hhat + base);
                bf16x8 ho;
                float hs = 0.f;
#pragma unroll
                for (int m = 0; m < 8; m++) {
                    float s = (float)s8[m];
                    float h = (float)h8[m];
                    float hn = ((1.f - s) * h + s * qv) * DEC[m];
                    ho[m] = (bf16_t)hn;
                    hs += hn;
                }
                *(bf16x8*)(hhat + base) = ho;
                hnext[(size_t)row * U_ + u] = (bf16_t)hs;
                htile[((((size_t)(row >> 8) * 8 + kt2) * 2 + ((row >> 7) & 1)) * 128
                       + (row & 127)) * 64
                      + (((kc >> 3) ^ (row & 7)) * 8) + (kc & 7)] = (bf16_t)hs;
            }
        }
    }
}

// dst[p][K_] = bf16(src[K_][NRS] col L), rows permuted within 64-groups.
__global__ void transpose_perm(const float* __restrict__ src, bf16_t* __restrict__ dst) {
    __shared__ float tl[32][33];
    int k0 = blockIdx.x * 32, n0 = blockIdx.y * 32;
    int tx = threadIdx.x & 31, ty = threadIdx.x >> 5;
#pragma unroll
    for (int i = 0; i < 32; i += 8)
        tl[ty + i][tx] = src[(size_t)(k0 + ty + i) * NRS + n0 + tx];
    __syncthreads();
#pragma unroll
    for (int i = 0; i < 32; i += 8) {
        int n = n0 + ty + i;
        int m = n & 7, u3v = (n >> 3) & 7;
        int p = (n & ~63) + (m & 3) * 16 + (m >> 2) * 8 + u3v;
        dst[(size_t)p * K_ + k0 + tx] = (bf16_t)tl[tx][ty + i];
    }
}

// Btile[np][kt][half][128][64] (swz baked) from WrsT [NC][K_] (perm rows).
__global__ void btile_build(const bf16_t* __restrict__ WrsT, bf16_t* __restrict__ Bt) {
    int n = blockIdx.x / 3;
    int k = (blockIdx.x % 3) * 256 + threadIdx.x;
    int np = n >> 8, rp = n & 255, hf = rp >> 7, r = rp & 127;
    int kt = k >> 6, kc = k & 63;
    Bt[((((size_t)np * 12 + kt) * 2 + hf) * 128 + r) * 64
       + (((kc >> 3) ^ (r & 7)) * 8) + (kc & 7)] = WrsT[(size_t)n * K_ + k];
}

// plain transpose: dst[N][K_] = bf16(src[K_][N]^T)
__global__ void transpose_plain(const float* __restrict__ src, bf16_t* __restrict__ dst, int N) {
    __shared__ float tl[32][33];
    int k0 = blockIdx.x * 32, n0 = blockIdx.y * 32;
    int tx = threadIdx.x & 31, ty = threadIdx.x >> 5;
#pragma unroll
    for (int i = 0; i < 32; i += 8)
        tl[ty + i][tx] = src[(size_t)(k0 + ty + i) * N + n0 + tx];
    __syncthreads();
#pragma unroll
    for (int i = 0; i < 32; i += 8)
        dst[(size_t)(n0 + ty + i) * K_ + k0 + tx] = (bf16_t)tl[tx][ty + i];
}

// Bqtile[np 0..7][kt 0..11][64][64] (swz baked) from WqT [U_][K_].
__global__ void bqtile_build(const bf16_t* __restrict__ WqT, bf16_t* __restrict__ Bqt) {
    int n = blockIdx.x / 3;
    int k = (blockIdx.x % 3) * 256 + threadIdx.x;
    int np = n >> 6, r = n & 63;
    int kt = k >> 6, kc = k & 63;
    Bqt[(((size_t)np * 12 + kt) * 64 + r) * 64
        + (((kc >> 3) ^ (r & 7)) * 8) + (kc & 7)] = WqT[(size_t)n * K_ + k];
}

__global__ void bias_perm(const float* __restrict__ b_r, const float* __restrict__ b_s,
                          float* __restrict__ biasP) {
    int p = blockIdx.x * 256 + threadIdx.x;  // NC
    int pr = p & 63, j = pr >> 4, lr = pr & 15;
    int L = (p & ~63) + (lr & 7) * 8 + ((lr >> 3) & 1) * 4 + j;
    biasP[p] = (L < NRS) ? b_r[L] : b_s[L - NRS];
}

// xtile[t][mp][kt][half][128][64] (swz baked) from x f32 [B][T][F].
__global__ void xtile_build(const float* __restrict__ x, bf16_t* __restrict__ xt) {
    int idx = blockIdx.x * 256 + threadIdx.x;  // B_*T_*F_
    int b = idx >> 12;
    int rem = idx & 4095;
    int t = rem >> 8, f = rem & 255;
    int mp = b >> 8, rp = b & 255, hf = rp >> 7, r = rp & 127;
    int kt = f >> 6, kc = f & 63;
    xt[(((((size_t)t * 16 + mp) * 4 + kt) * 2 + hf) * 128 + r) * 64
       + (((kc >> 3) ^ (r & 7)) * 8) + (kc & 7)] = (bf16_t)x[idx];
}

// One launch for all T steps: out[b,t,:] = hall[t][b][:] @ Wout + bout.
__global__ __launch_bounds__(256) void out_all(
    const bf16_t* __restrict__ hall,   // [T_][B_][U_] (slices 1..16 of alloc)
    const float* __restrict__ Wout,
    const float* __restrict__ bout,
    float* __restrict__ out)
{
    int row = blockIdx.x * 4 + (threadIdx.x >> 6);  // t*B_ + b
    int lane = threadIdx.x & 63;
    bf16x8 h8 = *(const bf16x8*)(hall + (size_t)row * U_ + lane * 8);
    float p0 = 0, p1 = 0, p2 = 0;
#pragma unroll
    for (int k = 0; k < 8; k++) {
        float h = (float)h8[k];
        int u = lane * 8 + k;
        p0 += h * Wout[u * 3 + 0];
        p1 += h * Wout[u * 3 + 1];
        p2 += h * Wout[u * 3 + 2];
    }
    for (int off = 32; off; off >>= 1) {
        p0 += __shfl_down(p0, off, 64);
        p1 += __shfl_down(p1, off, 64);
        p2 += __shfl_down(p2, off, 64);
    }
    if (lane == 0) {
        int t = row >> 12, b = row & (B_ - 1);
        size_t o = ((size_t)b * T_ + t) * 3;
        out[o + 0] = p0 + bout[0];
        out[o + 1] = p1 + bout[1];
        out[o + 2] = p2 + bout[2];
    }
}

extern "C" void kernel_launch(void* const* d_in, const int* in_sizes, int n_in,
                              void* d_out, int out_size, void* d_ws, size_t ws_size,
                              hipStream_t stream) {
    const float* x   = (const float*)d_in[0];
    const float* W_r = (const float*)d_in[1];
    const float* b_r = (const float*)d_in[2];
    const float* W_q = (const float*)d_in[3];
    const float* b_q = (const float*)d_in[4];
    const float* W_s = (const float*)d_in[5];
    const float* b_s = (const float*)d_in[6];
    const float* W_o = (const float*)d_in[7];
    const float* b_o = (const float*)d_in[8];
    float* out = (float*)d_out;

    char* ws = (char*)d_ws;
    bf16_t* hhat  = (bf16_t*)ws; ws += (size_t)B_ * NRS * 2;           // 33.5 MB
    bf16_t* sbuf  = (bf16_t*)ws; ws += (size_t)B_ * NRS * 2;           // 33.5 MB
    bf16_t* xtile = (bf16_t*)ws; ws += (size_t)B_ * T_ * F_ * 2;       // 33.5 MB
    bf16_t* hall  = (bf16_t*)ws; ws += (size_t)(T_ + 1) * B_ * U_ * 2; // 71 MB
    bf16_t* rh    = (bf16_t*)ws; ws += (size_t)B_ * U_ * 2;            // 4.2 MB
    bf16_t* WrsT  = (bf16_t*)ws; ws += (size_t)NC * K_ * 2;            // 12.6 MB
    bf16_t* Btile = (bf16_t*)ws; ws += (size_t)NC * K_ * 2;            // 12.6 MB
    bf16_t* htile = (bf16_t*)ws; ws += (size_t)B_ * U_ * 2;            // 4.2 MB
    bf16_t* WqT   = (bf16_t*)ws; ws += (size_t)U_ * K_ * 2;            // 0.79 MB
    bf16_t* Bqtil = (bf16_t*)ws; ws += (size_t)U_ * K_ * 2;            // 0.79 MB
    float*  biasP = (float*)ws;  ws += (size_t)NC * 4;                 // 32 KB

    hipMemsetAsync(hhat, 0, (size_t)B_ * NRS * 2, stream);
    hipMemsetAsync(htile, 0, (size_t)B_ * U_ * 2, stream);  // h(-1)=0 tiled
    xtile_build<<<B_ * T_ * F_ / 256, 256, 0, stream>>>(x, xtile);
    transpose_perm<<<dim3(K_ / 32, NRS / 32), 256, 0, stream>>>(W_r, WrsT);
    transpose_perm<<<dim3(K_ / 32, NRS / 32), 256, 0, stream>>>(W_s, WrsT + (size_t)NRS * K_);
    btile_build<<<NC * 3, 256, 0, stream>>>(WrsT, Btile);
    transpose_plain<<<dim3(K_ / 32, U_ / 32), 256, 0, stream>>>(W_q, WqT, U_);
    bqtile_build<<<U_ * 3, 256, 0, stream>>>(WqT, Bqtil);
    bias_perm<<<NC / 256, 256, 0, stream>>>(b_r, b_s, biasP);

    for (int t = 0; t < T_; t++) {
        const bf16_t* xt_t = xtile + (size_t)t * 16 * 4 * 2 * 8192;
        bf16_t*       hn   = hall + (size_t)(t + 1) * B_ * U_;  // h(t)
        gemm_rs_v8<<<dim3(16, 32), 512, 0, stream>>>(xt_t, htile, Btile, biasP, hhat, rh, sbuf);
        gemm_q_up<<<dim3(64, 8), 256, 0, stream>>>(xt_t, rh, Bqtil, b_q, sbuf, hhat, hn, htile);
    }
    out_all<<<B_ * T_ / 4, 256, 0, stream>>>(hall + (size_t)B_ * U_, W_o, b_o, out);
}

// Round 6
// 1753.416 us; speedup vs baseline: 1.0373x; 1.0373x over previous
//
#include <hip/hip_runtime.h>
#include <hip/hip_bf16.h>
#include <math.h>

#define B_   4096
#define T_   16
#define F_   256
#define U_   512
#define M_   8
#define K_   768    // F+U
#define NRS  4096   // U*M
#define NC   8192   // combined R|S output cols
#define LNT  1.1512925f  // 0.5*ln(10)

typedef __bf16 bf16_t;
typedef bf16_t bf16x8 __attribute__((ext_vector_type(8)));
typedef bf16_t bf16x4 __attribute__((ext_vector_type(4)));
typedef float  f32x4  __attribute__((ext_vector_type(4)));

__device__ inline void gl_lds16(const void* g, void* lds) {
    __builtin_amdgcn_global_load_lds(
        (const __attribute__((address_space(1))) unsigned int*)g,
        (__attribute__((address_space(3))) unsigned int*)lds, 16, 0, 0);
}

#define VMCNT(n) asm volatile("s_waitcnt vmcnt(" #n ")" ::: "memory")
#define LGKM0()  asm volatile("s_waitcnt lgkmcnt(0)" ::: "memory")
#define BAR()    __builtin_amdgcn_s_barrier()

// ---------------------------------------------------------------------------
// Half-tile format (pre-tiled): [128 rows][8 chunks][8 bf16] = 16 KB.
// Chunk q of row r holds SOURCE cols (q ^ (r&7))*8..+7 (swizzle baked into
// data). Staging = 4 linear 16B loads/thread (256 thr). Proven R4/R5.
// ---------------------------------------------------------------------------
__device__ inline void stage_ht(const bf16_t* src, bf16_t* dst, int tid) {
    gl_lds16(src + tid * 8,        (char*)dst + tid * 16);
    gl_lds16(src + tid * 8 + 2048, (char*)dst + tid * 16 + 4096);
    gl_lds16(src + tid * 8 + 4096, (char*)dst + tid * 16 + 8192);
    gl_lds16(src + tid * 8 + 6144, (char*)dst + tid * 16 + 12288);
}

// ---------------------------------------------------------------------------
// ABLATION SPLIT: gemm_half<1> = R columns (N 0..4095, r*hhat epilogue),
// gemm_half<0> = S columns (N 4096..8191, softmax->sbuf). Identical K-loops
// (R3's proven single-barrier parity schedule, pre-tiled linear operands),
// different epilogues -> separate rocprof rows isolate epilogue cost.
// 128x128 tile, 4 waves (2Mx2N), per-wave 64x64 acc[4][4]. LDS 64 KiB.
// ---------------------------------------------------------------------------
template <int IS_R>
__global__ __launch_bounds__(256, 4) void gemm_half(
    const bf16_t* __restrict__ xt_t,   // [16 mp][4 kt][2 half][128*64]
    const bf16_t* __restrict__ ht,     // [16 mp][8 kt][2 half][128*64]
    const bf16_t* __restrict__ Bt,     // [32 np][12 kt][2 half][128*64]
    const float*  __restrict__ biasP,  // [NC] (perm)
    const bf16_t* __restrict__ hhat,   // [B_][NRS]
    bf16_t* __restrict__ rh,           // [B_][U_]
    bf16_t* __restrict__ sbuf)         // [B_][NRS]
{
    __shared__ __attribute__((aligned(16))) bf16_t Ah[2][8192];  // 32 KiB
    __shared__ __attribute__((aligned(16))) bf16_t Bh[2][8192];  // 32 KiB

    const int tid  = threadIdx.x;
    const int lane = tid & 63;
    const int wave = tid >> 6;

    // bijective XCD swizzle: XCD c owns an 8mh x 16nh rectangle.
    const int lin = blockIdx.y * 32 + blockIdx.x;   // 1024 blocks
    const int c = lin & 7, q = lin >> 3;            // q: 0..127
    const int mh = (c >> 1) * 8 + (q & 7);          // 0..31 (128-row half)
    const int nh = (c & 1) * 16 + (q >> 3);         // 0..31
    const int m0 = mh * 128;
    const int NH = IS_R ? nh : 32 + nh;             // global 128-col half
    const int np = NH >> 1, nph = NH & 1;

    const int wm = wave >> 1;          // 0..1
    const int wn = wave & 1;           // 0..1
    const int lr = lane & 15;
    const int kq = lane >> 4;
    const int ck0 = (kq ^ (lr & 7)) * 8;   // ks=0 chunk byte-off; ks=1 -> ^32

    f32x4 acc[4][4] = {};
    bf16x8 a[4], b[4];

#define AS(T) ((T) < 4 ? xt_t + ((size_t)((mh >> 1) * 4 + (T)) * 2 + (mh & 1)) * 8192 \
                        : ht  + ((size_t)((mh >> 1) * 8 + (T) - 4) * 2 + (mh & 1)) * 8192)
#define BS(T) (Bt + ((size_t)(np * 12 + (T)) * 2 + nph) * 8192)

#define RD(dst, base, ks) do{                                                  \
    _Pragma("unroll") for (int i = 0; i < 4; ++i)                              \
        dst[i] = *(const bf16x8*)((base) + (i * 16 + lr) * 64 + (ck0 ^ ((ks) * 32))); \
  }while(0)

#define MMA() do{ __builtin_amdgcn_s_setprio(1);                               \
    _Pragma("unroll") for (int i = 0; i < 4; ++i)                              \
      _Pragma("unroll") for (int j = 0; j < 4; ++j)                            \
        acc[i][j] = __builtin_amdgcn_mfma_f32_16x16x32_bf16(                   \
            a[i], b[j], acc[i][j], 0, 0, 0);                                   \
    __builtin_amdgcn_s_setprio(0); }while(0)

    // Prologue: tile 0 staged, drained.
    stage_ht(AS(0), &Ah[0][0], tid);
    stage_ht(BS(0), &Bh[0][0], tid);
    VMCNT(0);
    BAR();

#define TILE(T, SFLAG)                                                         \
  {                                                                            \
    const int p_ = (T) & 1, pn_ = p_ ^ 1;                                      \
    if (SFLAG) {                                                               \
      stage_ht(AS((T) + 1), &Ah[pn_][0], tid);                                 \
      stage_ht(BS((T) + 1), &Bh[pn_][0], tid);                                 \
    }                                                                          \
    const bf16_t* Ab = &Ah[p_][0] + wm * 64 * 64;                              \
    const bf16_t* Bb = &Bh[p_][0] + wn * 64 * 64;                              \
    RD(a, Ab, 0); RD(b, Bb, 0);                                                \
    LGKM0();                                                                   \
    MMA();                                                                     \
    RD(a, Ab, 1); RD(b, Bb, 1);                                                \
    LGKM0();                                                                   \
    MMA();                                                                     \
    VMCNT(0);                                                                  \
    BAR();                                                                     \
  }

    TILE(0, 1);  TILE(1, 1);  TILE(2, 1);  TILE(3, 1);
    TILE(4, 1);  TILE(5, 1);  TILE(6, 1);  TILE(7, 1);
    TILE(8, 1);  TILE(9, 1);  TILE(10, 1); TILE(11, 0);
#undef TILE
#undef MMA
#undef RD
#undef AS
#undef BS

    // ------------------- fused softmax epilogue (proven math) --------------
    const int nb  = NH * 128 + wn * 64;   // global perm col base
    const int u3  = lane & 7;
    const int m0v = ((lane >> 3) & 1) * 4;

    float bj4[4];
#pragma unroll
    for (int j = 0; j < 4; ++j) bj4[j] = biasP[nb + j * 16 + lr];

#pragma unroll
    for (int mi = 0; mi < 4; ++mi) {
        const int rowb = m0 + wm * 64 + mi * 16 + kq * 4;
#pragma unroll
        for (int r = 0; r < 4; ++r) {
            const int row = rowb + r;
            float e[4], sum = 0.f;
#pragma unroll
            for (int j = 0; j < 4; ++j) {
                float v = acc[mi][j][r] + bj4[j];
                float d = v - (float)(m0v + j) * LNT;
                e[j] = __expf(-d * d);
                sum += e[j];
            }
            sum += __shfl_xor(sum, 8, 64);
            const float inv = 1.0f / sum;
            if (IS_R) {
                bf16x4 h4 = *(const bf16x4*)(hhat + (size_t)row * NRS + nb + u3 * 8 + m0v);
                float rhv = 0.f;
#pragma unroll
                for (int j = 0; j < 4; ++j) rhv += e[j] * inv * (float)h4[j];
                rhv += __shfl_xor(rhv, 8, 64);
                if ((lane & 8) == 0)
                    rh[(size_t)row * U_ + (nb >> 3) + u3] = (bf16_t)rhv;
            } else {
                bf16x4 pv;
#pragma unroll
                for (int j = 0; j < 4; ++j) pv[j] = (bf16_t)(e[j] * inv);
                *(bf16x4*)(sbuf + (size_t)row * NRS + (nb - NRS) + u3 * 8 + m0v) = pv;
            }
        }
    }
}

// ---------------------------------------------------------------------------
// q GEMM (64x64 tiles, grid 64x8=512, 4 waves 2x2) + fused state update.
// Unchanged from R5 (verified). Writes htile for the next step's gemm_half.
// ---------------------------------------------------------------------------
__global__ __launch_bounds__(256) void gemm_q_up(
    const bf16_t* __restrict__ xt_t,   // [16 mp][4 kt][2 half][128*64]
    const bf16_t* __restrict__ rh,     // [B_][U_]
    const bf16_t* __restrict__ Bqt,    // [8 np][12 kt][64*64] swz
    const float*  __restrict__ bq,
    const bf16_t* __restrict__ sbuf,
    bf16_t* __restrict__ hhat,
    bf16_t* __restrict__ hnext,        // hall slice t+1: [B_][U_]
    bf16_t* __restrict__ htile)        // [16 mp][8 kt][2 half][128*64]
{
    __shared__ __attribute__((aligned(16))) bf16_t As[4096];
    __shared__ __attribute__((aligned(16))) bf16_t Bs[4096];

    const int tid  = threadIdx.x;
    const int lane = tid & 63;
    const int wave = tid >> 6;
    const int m0 = blockIdx.x * 64;
    const int n0 = blockIdx.y * 64;
    const int wm = wave & 1;
    const int wn = wave >> 1;
    const int lr = lane & 15;
    const int kq = lane >> 4;
    const int ck0 = (kq ^ (lr & 7)) * 8;

    const int mp = m0 >> 8, half = (m0 >> 7) & 1, r0 = m0 & 127;
    const int rw = tid >> 3, q8 = tid & 7;

    f32x4 acc[2][2] = {};

    for (int kt = 0; kt < 12; ++kt) {
        __syncthreads();
        if (kt < 4) {
            const bf16_t* s = xt_t + ((size_t)(mp * 4 + kt) * 2 + half) * 8192 + r0 * 64;
            gl_lds16(s + tid * 8,        (char*)As + tid * 16);
            gl_lds16(s + tid * 8 + 2048, (char*)As + tid * 16 + 4096);
        } else {
            const int cb = (kt - 4) * 64;
            gl_lds16(rh + (size_t)(m0 + rw) * U_ + cb + ((q8 ^ (rw & 7)) * 8),
                     (char*)As + tid * 16);
            gl_lds16(rh + (size_t)(m0 + 32 + rw) * U_ + cb + ((q8 ^ (rw & 7)) * 8),
                     (char*)As + tid * 16 + 4096);
        }
        {
            const bf16_t* s = Bqt + (size_t)((n0 >> 6) * 12 + kt) * 4096;
            gl_lds16(s + tid * 8,        (char*)Bs + tid * 16);
            gl_lds16(s + tid * 8 + 2048, (char*)Bs + tid * 16 + 4096);
        }
        __syncthreads();

        bf16x8 af[4], bfr[4];
#pragma unroll
        for (int i = 0; i < 2; i++) {
            const bf16_t* pa = As + (wm * 32 + i * 16 + lr) * 64;
            const bf16_t* pb = Bs + (wn * 32 + i * 16 + lr) * 64;
            af[i * 2 + 0]  = *(const bf16x8*)(pa + ck0);
            af[i * 2 + 1]  = *(const bf16x8*)(pa + (ck0 ^ 32));
            bfr[i * 2 + 0] = *(const bf16x8*)(pb + ck0);
            bfr[i * 2 + 1] = *(const bf16x8*)(pb + (ck0 ^ 32));
        }
#pragma unroll
        for (int ks = 0; ks < 2; ks++)
#pragma unroll
            for (int i = 0; i < 2; i++)
#pragma unroll
                for (int j = 0; j < 2; j++)
                    acc[i][j] = __builtin_amdgcn_mfma_f32_16x16x32_bf16(
                        af[i * 2 + ks], bfr[j * 2 + ks], acc[i][j], 0, 0, 0);
    }

    const float DEC[8] = {0.0f, 0.9658531f, 0.9827783f, 0.9884856f,
                          0.9913518f, 0.9930754f, 0.9942261f, 0.9950489f};

#pragma unroll
    for (int i = 0; i < 2; i++) {
        const int rowb = m0 + wm * 32 + i * 16 + kq * 4;
#pragma unroll
        for (int j = 0; j < 2; j++) {
            const int u = n0 + wn * 32 + j * 16 + lr;
            const float bv = bq[u];
            const int kt2 = u >> 6, kc = u & 63;
#pragma unroll
            for (int r = 0; r < 4; r++) {
                const int row = rowb + r;
                const float qv = tanhf(acc[i][j][r] + bv);
                const size_t base = (size_t)row * NRS + u * 8;
                bf16x8 s8 = *(const bf16x8*)(sbuf + base);
                bf16x8 h8 = *(const bf16x8*)(hhat + base);
                bf16x8 ho;
                float hs = 0.f;
#pragma unroll
                for (int m = 0; m < 8; m++) {
                    float s = (float)s8[m];
                    float h = (float)h8[m];
                    float hn = ((1.f - s) * h + s * qv) * DEC[m];
                    ho[m] = (bf16_t)hn;
                    hs += hn;
                }
                *(bf16x8*)(hhat + base) = ho;
                hnext[(size_t)row * U_ + u] = (bf16_t)hs;
                htile[((((size_t)(row >> 8) * 8 + kt2) * 2 + ((row >> 7) & 1)) * 128
                       + (row & 127)) * 64
                      + (((kc >> 3) ^ (row & 7)) * 8) + (kc & 7)] = (bf16_t)hs;
            }
        }
    }
}

// dst[p][K_] = bf16(src[K_][NRS] col L), rows permuted within 64-groups.
__global__ void transpose_perm(const float* __restrict__ src, bf16_t* __restrict__ dst) {
    __shared__ float tl[32][33];
    int k0 = blockIdx.x * 32, n0 = blockIdx.y * 32;
    int tx = threadIdx.x & 31, ty = threadIdx.x >> 5;
#pragma unroll
    for (int i = 0; i < 32; i += 8)
        tl[ty + i][tx] = src[(size_t)(k0 + ty + i) * NRS + n0 + tx];
    __syncthreads();
#pragma unroll
    for (int i = 0; i < 32; i += 8) {
        int n = n0 + ty + i;
        int m = n & 7, u3v = (n >> 3) & 7;
        int p = (n & ~63) + (m & 3) * 16 + (m >> 2) * 8 + u3v;
        dst[(size_t)p * K_ + k0 + tx] = (bf16_t)tl[tx][ty + i];
    }
}

// Btile[np][kt][half][128][64] (swz baked) from WrsT [NC][K_] (perm rows).
__global__ void btile_build(const bf16_t* __restrict__ WrsT, bf16_t* __restrict__ Bt) {
    int n = blockIdx.x / 3;
    int k = (blockIdx.x % 3) * 256 + threadIdx.x;
    int np = n >> 8, rp = n & 255, hf = rp >> 7, r = rp & 127;
    int kt = k >> 6, kc = k & 63;
    Bt[((((size_t)np * 12 + kt) * 2 + hf) * 128 + r) * 64
       + (((kc >> 3) ^ (r & 7)) * 8) + (kc & 7)] = WrsT[(size_t)n * K_ + k];
}

// plain transpose: dst[N][K_] = bf16(src[K_][N]^T)
__global__ void transpose_plain(const float* __restrict__ src, bf16_t* __restrict__ dst, int N) {
    __shared__ float tl[32][33];
    int k0 = blockIdx.x * 32, n0 = blockIdx.y * 32;
    int tx = threadIdx.x & 31, ty = threadIdx.x >> 5;
#pragma unroll
    for (int i = 0; i < 32; i += 8)
        tl[ty + i][tx] = src[(size_t)(k0 + ty + i) * N + n0 + tx];
    __syncthreads();
#pragma unroll
    for (int i = 0; i < 32; i += 8)
        dst[(size_t)(n0 + ty + i) * K_ + k0 + tx] = (bf16_t)tl[tx][ty + i];
}

// Bqtile[np 0..7][kt 0..11][64][64] (swz baked) from WqT [U_][K_].
__global__ void bqtile_build(const bf16_t* __restrict__ WqT, bf16_t* __restrict__ Bqt) {
    int n = blockIdx.x / 3;
    int k = (blockIdx.x % 3) * 256 + threadIdx.x;
    int np = n >> 6, r = n & 63;
    int kt = k >> 6, kc = k & 63;
    Bqt[(((size_t)np * 12 + kt) * 64 + r) * 64
        + (((kc >> 3) ^ (r & 7)) * 8) + (kc & 7)] = WqT[(size_t)n * K_ + k];
}

__global__ void bias_perm(const float* __restrict__ b_r, const float* __restrict__ b_s,
                          float* __restrict__ biasP) {
    int p = blockIdx.x * 256 + threadIdx.x;  // NC
    int pr = p & 63, j = pr >> 4, lr = pr & 15;
    int L = (p & ~63) + (lr & 7) * 8 + ((lr >> 3) & 1) * 4 + j;
    biasP[p] = (L < NRS) ? b_r[L] : b_s[L - NRS];
}

// xtile[t][mp][kt][half][128][64] (swz baked) from x f32 [B][T][F].
__global__ void xtile_build(const float* __restrict__ x, bf16_t* __restrict__ xt) {
    int idx = blockIdx.x * 256 + threadIdx.x;  // B_*T_*F_
    int b = idx >> 12;
    int rem = idx & 4095;
    int t = rem >> 8, f = rem & 255;
    int mp = b >> 8, rp = b & 255, hf = rp >> 7, r = rp & 127;
    int kt = f >> 6, kc = f & 63;
    xt[(((((size_t)t * 16 + mp) * 4 + kt) * 2 + hf) * 128 + r) * 64
       + (((kc >> 3) ^ (r & 7)) * 8) + (kc & 7)] = (bf16_t)x[idx];
}

// One launch for all T steps: out[b,t,:] = hall[t][b][:] @ Wout + bout.
__global__ __launch_bounds__(256) void out_all(
    const bf16_t* __restrict__ hall,   // [T_][B_][U_] (slices 1..16 of alloc)
    const float* __restrict__ Wout,
    const float* __restrict__ bout,
    float* __restrict__ out)
{
    int row = blockIdx.x * 4 + (threadIdx.x >> 6);  // t*B_ + b
    int lane = threadIdx.x & 63;
    bf16x8 h8 = *(const bf16x8*)(hall + (size_t)row * U_ + lane * 8);
    float p0 = 0, p1 = 0, p2 = 0;
#pragma unroll
    for (int k = 0; k < 8; k++) {
        float h = (float)h8[k];
        int u = lane * 8 + k;
        p0 += h * Wout[u * 3 + 0];
        p1 += h * Wout[u * 3 + 1];
        p2 += h * Wout[u * 3 + 2];
    }
    for (int off = 32; off; off >>= 1) {
        p0 += __shfl_down(p0, off, 64);
        p1 += __shfl_down(p1, off, 64);
        p2 += __shfl_down(p2, off, 64);
    }
    if (lane == 0) {
        int t = row >> 12, b = row & (B_ - 1);
        size_t o = ((size_t)b * T_ + t) * 3;
        out[o + 0] = p0 + bout[0];
        out[o + 1] = p1 + bout[1];
        out[o + 2] = p2 + bout[2];
    }
}

extern "C" void kernel_launch(void* const* d_in, const int* in_sizes, int n_in,
                              void* d_out, int out_size, void* d_ws, size_t ws_size,
                              hipStream_t stream) {
    const float* x   = (const float*)d_in[0];
    const float* W_r = (const float*)d_in[1];
    const float* b_r = (const float*)d_in[2];
    const float* W_q = (const float*)d_in[3];
    const float* b_q = (const float*)d_in[4];
    const float* W_s = (const float*)d_in[5];
    const float* b_s = (const float*)d_in[6];
    const float* W_o = (const float*)d_in[7];
    const float* b_o = (const float*)d_in[8];
    float* out = (float*)d_out;

    char* ws = (char*)d_ws;
    bf16_t* hhat  = (bf16_t*)ws; ws += (size_t)B_ * NRS * 2;           // 33.5 MB
    bf16_t* sbuf  = (bf16_t*)ws; ws += (size_t)B_ * NRS * 2;           // 33.5 MB
    bf16_t* xtile = (bf16_t*)ws; ws += (size_t)B_ * T_ * F_ * 2;       // 33.5 MB
    bf16_t* hall  = (bf16_t*)ws; ws += (size_t)(T_ + 1) * B_ * U_ * 2; // 71 MB
    bf16_t* rh    = (bf16_t*)ws; ws += (size_t)B_ * U_ * 2;            // 4.2 MB
    bf16_t* WrsT  = (bf16_t*)ws; ws += (size_t)NC * K_ * 2;            // 12.6 MB
    bf16_t* Btile = (bf16_t*)ws; ws += (size_t)NC * K_ * 2;            // 12.6 MB
    bf16_t* htile = (bf16_t*)ws; ws += (size_t)B_ * U_ * 2;            // 4.2 MB
    bf16_t* WqT   = (bf16_t*)ws; ws += (size_t)U_ * K_ * 2;            // 0.79 MB
    bf16_t* Bqtil = (bf16_t*)ws; ws += (size_t)U_ * K_ * 2;            // 0.79 MB
    float*  biasP = (float*)ws;  ws += (size_t)NC * 4;                 // 32 KB

    hipMemsetAsync(hhat, 0, (size_t)B_ * NRS * 2, stream);
    hipMemsetAsync(htile, 0, (size_t)B_ * U_ * 2, stream);  // h(-1)=0 tiled
    xtile_build<<<B_ * T_ * F_ / 256, 256, 0, stream>>>(x, xtile);
    transpose_perm<<<dim3(K_ / 32, NRS / 32), 256, 0, stream>>>(W_r, WrsT);
    transpose_perm<<<dim3(K_ / 32, NRS / 32), 256, 0, stream>>>(W_s, WrsT + (size_t)NRS * K_);
    btile_build<<<NC * 3, 256, 0, stream>>>(WrsT, Btile);
    transpose_plain<<<dim3(K_ / 32, U_ / 32), 256, 0, stream>>>(W_q, WqT, U_);
    bqtile_build<<<U_ * 3, 256, 0, stream>>>(WqT, Bqtil);
    bias_perm<<<NC / 256, 256, 0, stream>>>(b_r, b_s, biasP);

    for (int t = 0; t < T_; t++) {
        const bf16_t* xt_t = xtile + (size_t)t * 16 * 4 * 2 * 8192;
        bf16_t*       hn   = hall + (size_t)(t + 1) * B_ * U_;  // h(t)
        gemm_half<1><<<dim3(32, 32), 256, 0, stream>>>(xt_t, htile, Btile, biasP, hhat, rh, sbuf);
        gemm_half<0><<<dim3(32, 32), 256, 0, stream>>>(xt_t, htile, Btile, biasP, hhat, rh, sbuf);
        gemm_q_up<<<dim3(64, 8), 256, 0, stream>>>(xt_t, rh, Bqtil, b_q, sbuf, hhat, hn, htile);
    }
    out_all<<<B_ * T_ / 4, 256, 0, stream>>>(hall + (size_t)B_ * U_, W_o, b_o, out);
}

// Round 7
// 1496.293 us; speedup vs baseline: 1.2156x; 1.1718x over previous
//
#include <hip/hip_runtime.h>
#include <hip/hip_bf16.h>
#include <math.h>

#define B_   4096
#define T_   16
#define F_   256
#define U_   512
#define M_   8
#define K_   768    // F+U
#define NRS  4096   // U*M
#define NC   8192   // combined R|S output cols
#define LNT  1.1512925f  // 0.5*ln(10)

// chunk-major pre-tiled panel constants
#define XPH  32768   // x panel per (t,mh): 8 kt * 4096
#define XPT  1048576 // x per t: 32 mh * XPH
#define HPH  65536   // h panel per mh: 16 kt * 4096
#define BPH  98304   // B panel per NH: 24 kt * 4096
#define QPH  49152   // Bq panel per np: 24 kt * 2048

typedef __bf16 bf16_t;
typedef bf16_t bf16x8 __attribute__((ext_vector_type(8)));
typedef bf16_t bf16x4 __attribute__((ext_vector_type(4)));
typedef float  f32x4  __attribute__((ext_vector_type(4)));

__device__ inline void gl_lds16(const void* g, void* lds) {
    __builtin_amdgcn_global_load_lds(
        (const __attribute__((address_space(1))) unsigned int*)g,
        (__attribute__((address_space(3))) unsigned int*)lds, 16, 0, 0);
}

#define VMCNT(n) asm volatile("s_waitcnt vmcnt(" #n ")" ::: "memory")
#define LGKM0()  asm volatile("s_waitcnt lgkmcnt(0)" ::: "memory")
#define BAR()    __builtin_amdgcn_s_barrier()

// ---------------------------------------------------------------------------
// Chunk-major BK=32 slot: [4 chunks][128 rows][8 bf16] = 8 KB. Chunk c holds
// k = c*8..c*8+7. Staging = 2 linear 16B loads/thread (256 thr). Reads: a
// quarter-wave (16 lanes, fixed chunk=kq) reads 16 consecutive rows x 16B ->
// 2 lanes per 16B bank-slot = free (no swizzle needed).
// ---------------------------------------------------------------------------
__device__ inline void stage8(const bf16_t* src, bf16_t* dst, int tid) {
    gl_lds16(src + tid * 8,        (char*)dst + tid * 16);
    gl_lds16(src + tid * 8 + 2048, (char*)dst + tid * 16 + 4096);
}

// ---------------------------------------------------------------------------
// R|S GEMM halves (ablation split kept): gemm_half<1> = R (r*hhat epilogue),
// gemm_half<0> = S (softmax->sbuf). 128x128 tile, 4 waves (2Mx2N), per-wave
// 64x64 acc[4][4]. BK=32, 24 K-tiles, single-barrier parity schedule.
// LDS 32 KiB -> 4 blocks/CU (grid 1024 = 4/CU, 16 waves/CU co-resident):
// the TLP experiment. VGPR ~88 -> launch_bounds(256,4) holds 4 blocks.
// ---------------------------------------------------------------------------
template <int IS_R>
__global__ __launch_bounds__(256, 4) void gemm_half(
    const bf16_t* __restrict__ xt_t,   // [32 mh][8 kt][4][128][8]
    const bf16_t* __restrict__ ht,     // [32 mh][16 kt][4][128][8]
    const bf16_t* __restrict__ Bt,     // [64 NH][24 kt][4][128][8]
    const float*  __restrict__ biasP,  // [NC] (perm)
    const bf16_t* __restrict__ hhat,   // [B_][NRS]
    bf16_t* __restrict__ rh,           // [B_][U_]
    bf16_t* __restrict__ sbuf)         // [B_][NRS]
{
    __shared__ __attribute__((aligned(16))) bf16_t Ahl[2][4096];  // 16 KiB
    __shared__ __attribute__((aligned(16))) bf16_t Bhl[2][4096];  // 16 KiB

    const int tid  = threadIdx.x;
    const int lane = tid & 63;
    const int wave = tid >> 6;

    // bijective XCD swizzle: XCD c owns an 8mh x 16nh rectangle.
    const int lin = blockIdx.y * 32 + blockIdx.x;   // 1024 blocks
    const int c = lin & 7, q = lin >> 3;            // q: 0..127
    const int mh = (c >> 1) * 8 + (q & 7);          // 0..31 (128-row half)
    const int nh = (c & 1) * 16 + (q >> 3);         // 0..31
    const int m0 = mh * 128;
    const int NH = IS_R ? nh : 32 + nh;             // global 128-col half

    const int wm = wave >> 1;          // 0..1
    const int wn = wave & 1;           // 0..1
    const int lr = lane & 15;
    const int kq = lane >> 4;          // chunk index (k-quarter of BK=32)

    const bf16_t* xp = xt_t + (size_t)mh * XPH;
    const bf16_t* hp = ht   + (size_t)mh * HPH;
    const bf16_t* bp = Bt   + (size_t)NH * BPH;

    const int aoff = kq * 1024 + (wm * 64 + lr) * 8;
    const int boff = kq * 1024 + (wn * 64 + lr) * 8;

    f32x4 acc[4][4] = {};

    // Prologue: tile 0 staged, drained.
    stage8(xp, &Ahl[0][0], tid);
    stage8(bp, &Bhl[0][0], tid);
    VMCNT(0);
    BAR();

#pragma unroll
    for (int tt = 0; tt < 24; ++tt) {
        const int p = tt & 1, pn = p ^ 1;
        if (tt < 23) {
            const bf16_t* as = (tt + 1 < 8) ? xp + (tt + 1) * 4096
                                            : hp + (tt + 1 - 8) * 4096;
            stage8(as, &Ahl[pn][0], tid);
            stage8(bp + (tt + 1) * 4096, &Bhl[pn][0], tid);
        }
        bf16x8 a[4], b[4];
#pragma unroll
        for (int i = 0; i < 4; ++i)
            a[i] = *(const bf16x8*)(&Ahl[p][0] + aoff + i * 128);
#pragma unroll
        for (int j = 0; j < 4; ++j)
            b[j] = *(const bf16x8*)(&Bhl[p][0] + boff + j * 128);
        LGKM0();
        __builtin_amdgcn_s_setprio(1);
#pragma unroll
        for (int i = 0; i < 4; ++i)
#pragma unroll
            for (int j = 0; j < 4; ++j)
                acc[i][j] = __builtin_amdgcn_mfma_f32_16x16x32_bf16(
                    a[i], b[j], acc[i][j], 0, 0, 0);
        __builtin_amdgcn_s_setprio(0);
        VMCNT(0);
        BAR();
    }

    // ------------------- fused softmax epilogue (proven math) --------------
    const int nb  = NH * 128 + wn * 64;   // global perm col base
    const int u3  = lane & 7;
    const int m0v = ((lane >> 3) & 1) * 4;

    float bj4[4];
#pragma unroll
    for (int j = 0; j < 4; ++j) bj4[j] = biasP[nb + j * 16 + lr];

#pragma unroll
    for (int mi = 0; mi < 4; ++mi) {
        const int rowb = m0 + wm * 64 + mi * 16 + kq * 4;
#pragma unroll
        for (int r = 0; r < 4; ++r) {
            const int row = rowb + r;
            float e[4], sum = 0.f;
#pragma unroll
            for (int j = 0; j < 4; ++j) {
                float v = acc[mi][j][r] + bj4[j];
                float d = v - (float)(m0v + j) * LNT;
                e[j] = __expf(-d * d);
                sum += e[j];
            }
            sum += __shfl_xor(sum, 8, 64);
            const float inv = 1.0f / sum;
            if (IS_R) {
                bf16x4 h4 = *(const bf16x4*)(hhat + (size_t)row * NRS + nb + u3 * 8 + m0v);
                float rhv = 0.f;
#pragma unroll
                for (int j = 0; j < 4; ++j) rhv += e[j] * inv * (float)h4[j];
                rhv += __shfl_xor(rhv, 8, 64);
                if ((lane & 8) == 0)
                    rh[(size_t)row * U_ + (nb >> 3) + u3] = (bf16_t)rhv;
            } else {
                bf16x4 pv;
#pragma unroll
                for (int j = 0; j < 4; ++j) pv[j] = (bf16_t)(e[j] * inv);
                *(bf16x4*)(sbuf + (size_t)row * NRS + (nb - NRS) + u3 * 8 + m0v) = pv;
            }
        }
    }
}

// ---------------------------------------------------------------------------
// q GEMM (64x64 tiles, grid 64x8=512, 4 waves 2x2) + fused state update.
// Same schedule as R5/R6; operand reads converted to the chunk-major format
// ([2 sub][4 ch][64][8] LDS slabs). Epilogue writes htile (chunk-major).
// ---------------------------------------------------------------------------
__global__ __launch_bounds__(256) void gemm_q_up(
    const bf16_t* __restrict__ xt_t,   // [32 mh][8 kt][4][128][8]
    const bf16_t* __restrict__ rh,     // [B_][U_]
    const bf16_t* __restrict__ Bqt,    // [8 np][24 kt][4][64][8]
    const float*  __restrict__ bq,
    const bf16_t* __restrict__ sbuf,
    bf16_t* __restrict__ hhat,
    bf16_t* __restrict__ hnext,        // hall slice t+1: [B_][U_]
    bf16_t* __restrict__ htile)        // [32 mh][16 kt][4][128][8]
{
    __shared__ __attribute__((aligned(16))) bf16_t As[4096];
    __shared__ __attribute__((aligned(16))) bf16_t Bs[4096];

    const int tid  = threadIdx.x;
    const int lane = tid & 63;
    const int wave = tid >> 6;
    const int m0 = blockIdx.x * 64;
    const int n0 = blockIdx.y * 64;
    const int wm = wave & 1;
    const int wn = wave >> 1;
    const int lr = lane & 15;
    const int kq = lane >> 4;

    const int chs = (tid >> 6) & 3;    // staging chunk
    const int rws = tid & 63;          // staging row

    const bf16_t* xp  = xt_t + (size_t)(m0 >> 7) * XPH;
    const int     r0  = m0 & 127;      // 0 or 64
    const bf16_t* bpq = Bqt + (size_t)(n0 >> 6) * QPH;

    f32x4 acc[2][2] = {};

    for (int kt = 0; kt < 12; ++kt) {
        __syncthreads();
        if (kt < 4) {
            gl_lds16(xp + ((size_t)((kt * 2 + 0) * 4 + chs) * 128 + r0 + rws) * 8,
                     (char*)As + tid * 16);
            gl_lds16(xp + ((size_t)((kt * 2 + 1) * 4 + chs) * 128 + r0 + rws) * 8,
                     (char*)As + tid * 16 + 4096);
        } else {
            const int cb = (kt - 4) * 64;
            gl_lds16(rh + (size_t)(m0 + rws) * U_ + cb + chs * 8,
                     (char*)As + tid * 16);
            gl_lds16(rh + (size_t)(m0 + rws) * U_ + cb + 32 + chs * 8,
                     (char*)As + tid * 16 + 4096);
        }
        gl_lds16(bpq + ((size_t)((kt * 2 + 0) * 4 + chs) * 64 + rws) * 8,
                 (char*)Bs + tid * 16);
        gl_lds16(bpq + ((size_t)((kt * 2 + 1) * 4 + chs) * 64 + rws) * 8,
                 (char*)Bs + tid * 16 + 4096);
        __syncthreads();

        bf16x8 af[4], bfr[4];
#pragma unroll
        for (int ks = 0; ks < 2; ks++)
#pragma unroll
            for (int i = 0; i < 2; i++) {
                af[i * 2 + ks]  = *(const bf16x8*)(As +
                    ((ks * 4 + kq) * 64 + wm * 32 + i * 16 + lr) * 8);
                bfr[i * 2 + ks] = *(const bf16x8*)(Bs +
                    ((ks * 4 + kq) * 64 + wn * 32 + i * 16 + lr) * 8);
            }
#pragma unroll
        for (int ks = 0; ks < 2; ks++)
#pragma unroll
            for (int i = 0; i < 2; i++)
#pragma unroll
                for (int j = 0; j < 2; j++)
                    acc[i][j] = __builtin_amdgcn_mfma_f32_16x16x32_bf16(
                        af[i * 2 + ks], bfr[j * 2 + ks], acc[i][j], 0, 0, 0);
    }

    const float DEC[8] = {0.0f, 0.9658531f, 0.9827783f, 0.9884856f,
                          0.9913518f, 0.9930754f, 0.9942261f, 0.9950489f};

#pragma unroll
    for (int i = 0; i < 2; i++) {
        const int rowb = m0 + wm * 32 + i * 16 + kq * 4;
#pragma unroll
        for (int j = 0; j < 2; j++) {
            const int u = n0 + wn * 32 + j * 16 + lr;
            const float bv = bq[u];
#pragma unroll
            for (int r = 0; r < 4; r++) {
                const int row = rowb + r;
                const float qv = tanhf(acc[i][j][r] + bv);
                const size_t base = (size_t)row * NRS + u * 8;
                bf16x8 s8 = *(const bf16x8*)(sbuf + base);
                bf16x8 h8 = *(const bf16x8*)(hhat + base);
                bf16x8 ho;
                float hs = 0.f;
#pragma unroll
                for (int m = 0; m < 8; m++) {
                    float s = (float)s8[m];
                    float h = (float)h8[m];
                    float hn = ((1.f - s) * h + s * qv) * DEC[m];
                    ho[m] = (bf16_t)hn;
                    hs += hn;
                }
                *(bf16x8*)(hhat + base) = ho;
                hnext[(size_t)row * U_ + u] = (bf16_t)hs;
                htile[((size_t)(row >> 7) * 16 + (u >> 5)) * 4096
                      + ((((u >> 3) & 3) * 128) + (row & 127)) * 8 + (u & 7)] = (bf16_t)hs;
            }
        }
    }
}

// dst[p][K_] = bf16(src[K_][NRS] col L), rows permuted within 64-groups.
__global__ void transpose_perm(const float* __restrict__ src, bf16_t* __restrict__ dst) {
    __shared__ float tl[32][33];
    int k0 = blockIdx.x * 32, n0 = blockIdx.y * 32;
    int tx = threadIdx.x & 31, ty = threadIdx.x >> 5;
#pragma unroll
    for (int i = 0; i < 32; i += 8)
        tl[ty + i][tx] = src[(size_t)(k0 + ty + i) * NRS + n0 + tx];
    __syncthreads();
#pragma unroll
    for (int i = 0; i < 32; i += 8) {
        int n = n0 + ty + i;
        int m = n & 7, u3v = (n >> 3) & 7;
        int p = (n & ~63) + (m & 3) * 16 + (m >> 2) * 8 + u3v;
        dst[(size_t)p * K_ + k0 + tx] = (bf16_t)tl[tx][ty + i];
    }
}

// BtN[NH][kt][4][128][8] (chunk-major) from WrsT [NC][K_] (perm rows).
__global__ void btile_build(const bf16_t* __restrict__ WrsT, bf16_t* __restrict__ Bt) {
    int n = blockIdx.x / 3;
    int k = (blockIdx.x % 3) * 256 + threadIdx.x;
    int NH = n >> 7, prow = n & 127;
    int kt = k >> 5, ch = (k >> 3) & 3, e = k & 7;
    Bt[(size_t)NH * BPH + (((size_t)kt * 4 + ch) * 128 + prow) * 8 + e]
        = WrsT[(size_t)n * K_ + k];
}

// plain transpose: dst[N][K_] = bf16(src[K_][N]^T)
__global__ void transpose_plain(const float* __restrict__ src, bf16_t* __restrict__ dst, int N) {
    __shared__ float tl[32][33];
    int k0 = blockIdx.x * 32, n0 = blockIdx.y * 32;
    int tx = threadIdx.x & 31, ty = threadIdx.x >> 5;
#pragma unroll
    for (int i = 0; i < 32; i += 8)
        tl[ty + i][tx] = src[(size_t)(k0 + ty + i) * N + n0 + tx];
    __syncthreads();
#pragma unroll
    for (int i = 0; i < 32; i += 8)
        dst[(size_t)(n0 + ty + i) * K_ + k0 + tx] = (bf16_t)tl[tx][ty + i];
}

// BqtN[np][kt][4][64][8] (chunk-major) from WqT [U_][K_].
__global__ void bqtile_build(const bf16_t* __restrict__ WqT, bf16_t* __restrict__ Bqt) {
    int n = blockIdx.x / 3;
    int k = (blockIdx.x % 3) * 256 + threadIdx.x;
    int np = n >> 6, prow = n & 63;
    int kt = k >> 5, ch = (k >> 3) & 3, e = k & 7;
    Bqt[(size_t)np * QPH + (((size_t)kt * 4 + ch) * 64 + prow) * 8 + e]
        = WqT[(size_t)n * K_ + k];
}

__global__ void bias_perm(const float* __restrict__ b_r, const float* __restrict__ b_s,
                          float* __restrict__ biasP) {
    int p = blockIdx.x * 256 + threadIdx.x;  // NC
    int pr = p & 63, j = pr >> 4, lr = pr & 15;
    int L = (p & ~63) + (lr & 7) * 8 + ((lr >> 3) & 1) * 4 + j;
    biasP[p] = (L < NRS) ? b_r[L] : b_s[L - NRS];
}

// xtN[t][mh][kt][4][128][8] (chunk-major) from x f32 [B][T][F].
__global__ void xtile_build(const float* __restrict__ x, bf16_t* __restrict__ xt) {
    int idx = blockIdx.x * 256 + threadIdx.x;  // B_*T_*F_
    int b = idx >> 12;
    int rem = idx & 4095;
    int t = rem >> 8, f = rem & 255;
    int mh = b >> 7, prow = b & 127;
    int kt = f >> 5, ch = (f >> 3) & 3, e = f & 7;
    xt[(size_t)t * XPT + (size_t)mh * XPH
       + (((size_t)kt * 4 + ch) * 128 + prow) * 8 + e] = (bf16_t)x[idx];
}

// One launch for all T steps: out[b,t,:] = hall[t][b][:] @ Wout + bout.
__global__ __launch_bounds__(256) void out_all(
    const bf16_t* __restrict__ hall,   // [T_][B_][U_] (slices 1..16 of alloc)
    const float* __restrict__ Wout,
    const float* __restrict__ bout,
    float* __restrict__ out)
{
    int row = blockIdx.x * 4 + (threadIdx.x >> 6);  // t*B_ + b
    int lane = threadIdx.x & 63;
    bf16x8 h8 = *(const bf16x8*)(hall + (size_t)row * U_ + lane * 8);
    float p0 = 0, p1 = 0, p2 = 0;
#pragma unroll
    for (int k = 0; k < 8; k++) {
        float h = (float)h8[k];
        int u = lane * 8 + k;
        p0 += h * Wout[u * 3 + 0];
        p1 += h * Wout[u * 3 + 1];
        p2 += h * Wout[u * 3 + 2];
    }
    for (int off = 32; off; off >>= 1) {
        p0 += __shfl_down(p0, off, 64);
        p1 += __shfl_down(p1, off, 64);
        p2 += __shfl_down(p2, off, 64);
    }
    if (lane == 0) {
        int t = row >> 12, b = row & (B_ - 1);
        size_t o = ((size_t)b * T_ + t) * 3;
        out[o + 0] = p0 + bout[0];
        out[o + 1] = p1 + bout[1];
        out[o + 2] = p2 + bout[2];
    }
}

extern "C" void kernel_launch(void* const* d_in, const int* in_sizes, int n_in,
                              void* d_out, int out_size, void* d_ws, size_t ws_size,
                              hipStream_t stream) {
    const float* x   = (const float*)d_in[0];
    const float* W_r = (const float*)d_in[1];
    const float* b_r = (const float*)d_in[2];
    const float* W_q = (const float*)d_in[3];
    const float* b_q = (const float*)d_in[4];
    const float* W_s = (const float*)d_in[5];
    const float* b_s = (const float*)d_in[6];
    const float* W_o = (const float*)d_in[7];
    const float* b_o = (const float*)d_in[8];
    float* out = (float*)d_out;

    char* ws = (char*)d_ws;
    bf16_t* hhat  = (bf16_t*)ws; ws += (size_t)B_ * NRS * 2;           // 33.5 MB
    bf16_t* sbuf  = (bf16_t*)ws; ws += (size_t)B_ * NRS * 2;           // 33.5 MB
    bf16_t* xtile = (bf16_t*)ws; ws += (size_t)T_ * XPT * 2;           // 33.5 MB
    bf16_t* hall  = (bf16_t*)ws; ws += (size_t)(T_ + 1) * B_ * U_ * 2; // 71 MB
    bf16_t* rh    = (bf16_t*)ws; ws += (size_t)B_ * U_ * 2;            // 4.2 MB
    bf16_t* WrsT  = (bf16_t*)ws; ws += (size_t)NC * K_ * 2;            // 12.6 MB
    bf16_t* Btile = (bf16_t*)ws; ws += (size_t)NC * K_ * 2;            // 12.6 MB
    bf16_t* htile = (bf16_t*)ws; ws += (size_t)32 * HPH * 2;           // 4.2 MB
    bf16_t* WqT   = (bf16_t*)ws; ws += (size_t)U_ * K_ * 2;            // 0.79 MB
    bf16_t* Bqtil = (bf16_t*)ws; ws += (size_t)8 * QPH * 2;            // 0.79 MB
    float*  biasP = (float*)ws;  ws += (size_t)NC * 4;                 // 32 KB

    hipMemsetAsync(hhat, 0, (size_t)B_ * NRS * 2, stream);
    hipMemsetAsync(htile, 0, (size_t)32 * HPH * 2, stream);  // h(-1)=0 tiled
    xtile_build<<<B_ * T_ * F_ / 256, 256, 0, stream>>>(x, xtile);
    transpose_perm<<<dim3(K_ / 32, NRS / 32), 256, 0, stream>>>(W_r, WrsT);
    transpose_perm<<<dim3(K_ / 32, NRS / 32), 256, 0, stream>>>(W_s, WrsT + (size_t)NRS * K_);
    btile_build<<<NC * 3, 256, 0, stream>>>(WrsT, Btile);
    transpose_plain<<<dim3(K_ / 32, U_ / 32), 256, 0, stream>>>(W_q, WqT, U_);
    bqtile_build<<<U_ * 3, 256, 0, stream>>>(WqT, Bqtil);
    bias_perm<<<NC / 256, 256, 0, stream>>>(b_r, b_s, biasP);

    for (int t = 0; t < T_; t++) {
        const bf16_t* xt_t = xtile + (size_t)t * XPT;
        bf16_t*       hn   = hall + (size_t)(t + 1) * B_ * U_;  // h(t)
        gemm_half<1><<<dim3(32, 32), 256, 0, stream>>>(xt_t, htile, Btile, biasP, hhat, rh, sbuf);
        gemm_half<0><<<dim3(32, 32), 256, 0, stream>>>(xt_t, htile, Btile, biasP, hhat, rh, sbuf);
        gemm_q_up<<<dim3(64, 8), 256, 0, stream>>>(xt_t, rh, Bqtil, b_q, sbuf, hhat, hn, htile);
    }
    out_all<<<B_ * T_ / 4, 256, 0, stream>>>(hall + (size_t)B_ * U_, W_o, b_o, out);
}